// Round 15
// baseline (68.279 us; speedup 1.0000x reference)
//
#include <hip/hip_runtime.h>
#include <math.h>

// Problem shape (fixed by harness reference)
#define B_SZ 32
#define NM   2048     // N == M == 2048
#define D_SZ 32
#define NH   4        // M-quarters per direction
#define TPH  32       // tiles per block sweep = 128/NH

typedef __attribute__((ext_vector_type(8))) _Float16 h8;   // MFMA A/B frag
typedef __attribute__((ext_vector_type(4))) float f4;      // MFMA C/D frag

// ---------------------------------------------------------------------------
// Pack X (and Y) into MFMA-fragment-ready f16 layout + fused HALF squared
// norms ph = +0.5*||row||^2 (exact fp32; layout verified absmax 0.0 r2-r14).
// Also zero-inits the fixed-point accumulator pair (graph-replay safe).
// ---------------------------------------------------------------------------
__global__ __launch_bounds__(256)
void pack_kernel(const float* __restrict__ srcX, const float* __restrict__ srcY,
                 h8* __restrict__ dstX, h8* __restrict__ dstY,
                 float* __restrict__ phX, float* __restrict__ phY,
                 unsigned long long* __restrict__ acc)
{
    const int gid = blockIdx.x * 256 + threadIdx.x;
    if (blockIdx.y == 0 && gid < 2) acc[gid] = 0ULL;   // [0]=sum, [1]=counter

    const float* src = blockIdx.y ? srcY : srcX;
    h8*          dst = blockIdx.y ? dstY : dstX;
    float*       ph  = blockIdx.y ? phY  : phX;

    const int l   = gid & 63;
    const int t   = gid >> 6;
    const int row = t * 16 + (l & 15);
    const int k0  = (l >> 4) * 4;

    const float* p = src + (size_t)row * D_SZ;
    f4 v0 = *(const f4*)(p + k0);
    f4 v1 = *(const f4*)(p + 16 + k0);

    h8 h;
    h[0] = (_Float16)v0[0]; h[1] = (_Float16)v0[1];
    h[2] = (_Float16)v0[2]; h[3] = (_Float16)v0[3];
    h[4] = (_Float16)v1[0]; h[5] = (_Float16)v1[1];
    h[6] = (_Float16)v1[2]; h[7] = (_Float16)v1[3];
    dst[gid] = h;

    float s = 0.f;
#pragma unroll
    for (int j = 0; j < 4; ++j) {
        s = fmaf(v0[j], v0[j], s);
        s = fmaf(v1[j], v1[j], s);
    }
    s += __shfl_xor(s, 16);
    s += __shfl_xor(s, 32);
    if (l < 16) ph[row] = 0.5f * s;      // +0.5 * ||row||^2
}

// ---------------------------------------------------------------------------
// One directional pass, r6-verified body. dir=0: rows=X, cols=Y; dir=1
// swapped. Round 15 combination (first test of TLP + pipeline + locality all
// intact simultaneously):
//  - NH=4 -> 2048 blocks; __launch_bounds__(256,6) (~85 VGPR cap) keeps the
//    depth-4 prefetch registers live (r8 lesson: the (256,8)=64 cap collapsed
//    the pipeline to VGPR=32) while giving 6 blocks/CU = 6 waves/SIMD;
//  - b-major XCD grouping (r10): each XCD owns 4 COMPLETE batches ~1.1MB <<
//    4MB private L2 (r8's z-major spread 10MB/XCD -> 290MB HBM; this is the
//    locality-safe high-occupancy config).
// C-seed = -ph[col] (ph = +0.5*norm):
//     min_j d2[i,j] = 2*ph_p[i] - 2 * max_j (dot[i,j] - ph_q[j])
// End: shfl-max over 16 col-lanes, lc==0 lanes store rows directly.
// C/D layout (m89-verified): col=lane&15, row=(lane>>4)*4+reg.
// ---------------------------------------------------------------------------
#define PASS_BODY(BF, CV)                                                     \
    {                                                                         \
        const float ch_ = -(CV);                                              \
        const f4 cs_ = {ch_, ch_, ch_, ch_};                                  \
        f4 q0 = __builtin_amdgcn_mfma_f32_16x16x32_f16(a0, (BF), cs_, 0,0,0); \
        f4 q1 = __builtin_amdgcn_mfma_f32_16x16x32_f16(a1, (BF), cs_, 0,0,0); \
        f4 q2 = __builtin_amdgcn_mfma_f32_16x16x32_f16(a2, (BF), cs_, 0,0,0); \
        f4 q3 = __builtin_amdgcn_mfma_f32_16x16x32_f16(a3, (BF), cs_, 0,0,0); \
        _Pragma("unroll")                                                     \
        for (int r = 0; r < 4; ++r) {                                         \
            mx0[r] = fmaxf(mx0[r], q0[r]);                                    \
            mx1[r] = fmaxf(mx1[r], q1[r]);                                    \
            mx2[r] = fmaxf(mx2[r], q2[r]);                                    \
            mx3[r] = fmaxf(mx3[r], q3[r]);                                    \
        }                                                                     \
    }

__global__ __launch_bounds__(256, 6)
void chamfer_pass(const h8* __restrict__ Xpk, const h8* __restrict__ Ypk,
                  const float* __restrict__ phX, const float* __restrict__ phY,
                  float* __restrict__ mp)
{
    // b-major XCD swizzle: nwg = 2048, phys%8 = XCD -> lg chunks of 256 = 4
    // complete batches per XCD. Decode with b slowest.
    const int phys = blockIdx.x;
    const int lg   = (phys & 7) * 256 + (phys >> 3);
    const int b    = lg >> 6;            // 64 blocks per batch
    const int inner= lg & 63;
    const int dir  = inner >> 5;
    const int rr   = inner & 31;
    const int half = rr >> 3;            // 0..3
    const int xb   = rr & 7;             // 8 row-blocks of 256 rows

    const int tid = threadIdx.x;
    const int w   = tid >> 6;
    const int l   = tid & 63;
    const int lc  = l & 15;
    const int g   = l >> 4;

    const h8* Ppk = dir ? Ypk : Xpk;
    const h8* Qpk = dir ? Xpk : Ypk;
    const float* qn = dir ? phX : phY;

    const int row0 = xb * 256 + w * 64;                   // within batch
    const size_t pt0 = ((size_t)b * NM + row0) >> 4;      // global 16-row tile
    const h8* pa = Ppk + pt0 * 64 + l;
    h8 a0 = pa[0], a1 = pa[64], a2 = pa[128], a3 = pa[192];

    const int mt0 = half * TPH;
    const h8*    qb  = Qpk + ((size_t)b * (NM / 16) + mt0) * 64 + l;
    const float* qnb = qn + (size_t)b * NM + mt0 * 16 + lc;

    const float NEGINF = -3.0e38f;
    f4 mx0 = {NEGINF, NEGINF, NEGINF, NEGINF};
    f4 mx1 = mx0, mx2 = mx0, mx3 = mx0;

    // 4-deep register prefetch pipeline (TPH = 32, multiple of 4)
    h8 b0 = qb[0], b1 = qb[64], b2 = qb[128], b3 = qb[192];
    float c0 = qnb[0], c1 = qnb[16], c2 = qnb[32], c3 = qnb[48];

    for (int t = 0; t < TPH - 4; t += 4) {
        qb += 4 * 64; qnb += 4 * 16;
        h8 n0 = qb[0], n1 = qb[64], n2 = qb[128], n3 = qb[192];
        float d0 = qnb[0], d1 = qnb[16], d2 = qnb[32], d3 = qnb[48];
        PASS_BODY(b0, c0);
        PASS_BODY(b1, c1);
        PASS_BODY(b2, c2);
        PASS_BODY(b3, c3);
        b0 = n0; b1 = n1; b2 = n2; b3 = n3;
        c0 = d0; c1 = d1; c2 = d2; c3 = d3;
    }
    PASS_BODY(b0, c0);       // tail batch
    PASS_BODY(b1, c1);
    PASS_BODY(b2, c2);
    PASS_BODY(b3, c3);

    // reduce max across the 16 column-lanes
#pragma unroll
    for (int m = 1; m <= 8; m <<= 1) {
#pragma unroll
        for (int r = 0; r < 4; ++r) {
            mx0[r] = fmaxf(mx0[r], __shfl_xor(mx0[r], m));
            mx1[r] = fmaxf(mx1[r], __shfl_xor(mx1[r], m));
            mx2[r] = fmaxf(mx2[r], __shfl_xor(mx2[r], m));
            mx3[r] = fmaxf(mx3[r], __shfl_xor(mx3[r], m));
        }
    }
    if (lc == 0) {   // 4 lanes per wave; rows row0 + i*16 + g*4 .. +3
        float* out = mp + ((size_t)(dir * NH + half) * B_SZ + b) * NM
                        + row0 + (g << 2);
        *(f4*)(out)      = mx0;
        *(f4*)(out + 16) = mx1;
        *(f4*)(out + 32) = mx2;
        *(f4*)(out + 48) = mx3;
    }
}

// ---------------------------------------------------------------------------
// Merged finalize (r14-verified pattern): d2 = 2*(ph - max(4 halves)), clamp,
// sqrt, block tree-sum, deterministic fixed-point u64 atomicAdd, last-done
// block writes out[0]. 32768 threads = 128 blocks x 256, one f4 per thread.
// ---------------------------------------------------------------------------
__global__ __launch_bounds__(256)
void finalize_one(const float* __restrict__ mp, const float* __restrict__ ph,
                  unsigned long long* __restrict__ acc, float* __restrict__ out)
{
    const int i   = blockIdx.x * 256 + threadIdx.x;   // 0..32767
    const int dir = i >> 14;
    const int r4  = i & 16383;
    const f4* mb = (const f4*)mp + (size_t)dir * NH * 16384;
    f4 pm = mb[r4];
#pragma unroll
    for (int h = 1; h < NH; ++h) {
        f4 v = mb[(size_t)h * 16384 + r4];
#pragma unroll
        for (int r = 0; r < 4; ++r) pm[r] = fmaxf(pm[r], v[r]);
    }
    f4 nv = ((const f4*)(ph + (size_t)dir * 65536))[r4];
    float s = 0.f;
#pragma unroll
    for (int r = 0; r < 4; ++r) {
        float d2 = 2.f * (nv[r] - pm[r]);
        s += sqrtf(fmaxf(d2, 0.f));
    }
    __shared__ float wsum[4];
#pragma unroll
    for (int o = 32; o > 0; o >>= 1) s += __shfl_down(s, o, 64);
    if ((threadIdx.x & 63) == 0) wsum[threadIdx.x >> 6] = s;
    __syncthreads();
    if (threadIdx.x == 0) {
        float bs = wsum[0] + wsum[1] + wsum[2] + wsum[3];
        unsigned long long v =
            (unsigned long long)llrint((double)bs * 1048576.0);
        atomicAdd(&acc[0], v);
        __threadfence();
        unsigned long long c = atomicAdd(&acc[1], 1ULL);
        if (c == 127ULL) {
            unsigned long long tot = atomicAdd(&acc[0], 0ULL);
            out[0] = (float)((double)tot * (1.0 / (131072.0 * 1048576.0)));
        }
    }
}

extern "C" void kernel_launch(void* const* d_in, const int* in_sizes, int n_in,
                              void* d_out, int out_size, void* d_ws, size_t ws_size,
                              hipStream_t stream) {
    const float* X = (const float*)d_in[0];
    const float* Y = (const float*)d_in[1];

    // ws: mp 2*NH*65536 f (2MB) | acc 2 u64 | ph 131072 f | packed 8.39MB
    float*              ws  = (float*)d_ws;
    float*              mp  = ws;                               // 524288 f
    unsigned long long* acc = (unsigned long long*)(mp + 524288);
    float*              ph  = (float*)(acc + 2);                // 131072 f
    h8*                 Xpk = (h8*)(ph + 131072);               // 4.19 MB
    h8*                 Ypk = Xpk + 262144;                     // 4.19 MB

    dim3 pgrid(1024, 2);
    pack_kernel<<<pgrid, 256, 0, stream>>>(X, Y, Xpk, Ypk, ph, ph + 65536, acc);

    // 2048 blocks = 8 rb x 32 b x 2 dir x 4 half, b-major XCD-swizzled inside
    chamfer_pass<<<8 * B_SZ * 2 * NH, 256, 0, stream>>>(Xpk, Ypk, ph, ph + 65536,
                                                        mp);

    finalize_one<<<128, 256, 0, stream>>>(mp, ph, acc, (float*)d_out);
}

// Round 16
// 36.373 us; speedup vs baseline: 1.8772x; 1.8772x over previous
//
#include <hip/hip_runtime.h>
#include <math.h>

// Problem shape (fixed by harness reference)
#define B_SZ 32
#define NM   2048     // N == M == 2048
#define D_SZ 32

typedef __attribute__((ext_vector_type(8))) _Float16 h8;   // MFMA A/B frag: 8 f16 = 4 VGPRs
typedef __attribute__((ext_vector_type(4))) float f4;      // MFMA C/D frag

// ---------------------------------------------------------------------------
// Pack X (and Y) into MFMA-fragment-ready f16 layout + fused HALF squared
// norms ph = +0.5*||row||^2 (exact fp32). Fragment layout verified absmax 0.0
// in rounds 2-14. Also initializes colkey (0xFFFFFFFF) and the fixed-point
// accumulator/counter pair — 3-dispatch launch graph. Re-inits every call
// (stream-ordered before chamfer/finalize) -> graph-replay safe.
// ---------------------------------------------------------------------------
__global__ __launch_bounds__(256)
void pack_kernel(const float* __restrict__ srcX, const float* __restrict__ srcY,
                 h8* __restrict__ dstX, h8* __restrict__ dstY,
                 float* __restrict__ phX, float* __restrict__ phY,
                 unsigned int* __restrict__ colkey,
                 unsigned long long* __restrict__ acc)
{
    const int gid = blockIdx.x * 256 + threadIdx.x;   // one thread per (tile,lane)
    if (blockIdx.y == 0) {
        if (gid < 65536) colkey[gid] = 0xFFFFFFFFu;   // max uint sentinel
        if (gid < 2)     acc[gid]    = 0ULL;          // [0]=sum, [1]=counter
    }
    const float* src = blockIdx.y ? srcY : srcX;
    h8*          dst = blockIdx.y ? dstY : dstX;
    float*       ph  = blockIdx.y ? phY  : phX;

    const int l   = gid & 63;
    const int t   = gid >> 6;
    const int row = t * 16 + (l & 15);
    const int k0  = (l >> 4) * 4;

    const float* p = src + (size_t)row * D_SZ;
    f4 v0 = *(const f4*)(p + k0);        // k = k0..k0+3
    f4 v1 = *(const f4*)(p + 16 + k0);   // k = 16+k0..16+k0+3

    h8 h;
    h[0] = (_Float16)v0[0]; h[1] = (_Float16)v0[1];
    h[2] = (_Float16)v0[2]; h[3] = (_Float16)v0[3];
    h[4] = (_Float16)v1[0]; h[5] = (_Float16)v1[1];
    h[6] = (_Float16)v1[2]; h[7] = (_Float16)v1[3];
    dst[gid] = h;

    float s = 0.f;
#pragma unroll
    for (int j = 0; j < 4; ++j) {
        s = fmaf(v0[j], v0[j], s);
        s = fmaf(v1[j], v1[j], s);
    }
    s += __shfl_xor(s, 16);
    s += __shfl_xor(s, 32);
    if (l < 16) ph[row] = 0.5f * s;      // +0.5 * ||row||^2
}

// ---------------------------------------------------------------------------
// FUSED one-pass (verified absmax 0.0 r13/r14): both directions in a single
// sweep. s = dot - 0.5||x||^2 - 0.5||y||^2 = -0.5 d^2.
// Row side: register fmax + end shuffles; col side: per-tile in-lane tree +
// shfl_xor(16,32) + predicated LDS store, cross-wave combine after ONE
// barrier, one idempotent uint atomicMin per column (s<=0: min-on-bits ==
// max-on-float -> deterministic). z-major XCD swizzle (verified r5), 4 waves
// sweep the SAME B-stream, depth-4 prefetch (verified r6), (256,2) no-spill
// (verified r12). C/D layout (m89): col=lane&15, row=(lane>>4)*4+reg.
// ---------------------------------------------------------------------------
#define PASS1(BF, PH, T)                                                      \
    {                                                                         \
        f4 q0 = __builtin_amdgcn_mfma_f32_16x16x32_f16(a0, (BF), hx0, 0,0,0); \
        f4 q1 = __builtin_amdgcn_mfma_f32_16x16x32_f16(a1, (BF), hx1, 0,0,0); \
        f4 q2 = __builtin_amdgcn_mfma_f32_16x16x32_f16(a2, (BF), hx2, 0,0,0); \
        f4 q3 = __builtin_amdgcn_mfma_f32_16x16x32_f16(a3, (BF), hx3, 0,0,0); \
        _Pragma("unroll")                                                     \
        for (int r = 0; r < 4; ++r) {                                         \
            q0[r] -= (PH); q1[r] -= (PH); q2[r] -= (PH); q3[r] -= (PH);       \
            mx0[r] = fmaxf(mx0[r], q0[r]);                                    \
            mx1[r] = fmaxf(mx1[r], q1[r]);                                    \
            mx2[r] = fmaxf(mx2[r], q2[r]);                                    \
            mx3[r] = fmaxf(mx3[r], q3[r]);                                    \
        }                                                                     \
        float m0 = fmaxf(fmaxf(q0[0], q0[1]), fmaxf(q0[2], q0[3]));          \
        float m1 = fmaxf(fmaxf(q1[0], q1[1]), fmaxf(q1[2], q1[3]));          \
        float m2 = fmaxf(fmaxf(q2[0], q2[1]), fmaxf(q2[2], q2[3]));          \
        float m3 = fmaxf(fmaxf(q3[0], q3[1]), fmaxf(q3[2], q3[3]));          \
        float cm = fmaxf(fmaxf(m0, m1), fmaxf(m2, m3));                       \
        cm = fmaxf(cm, __shfl_xor(cm, 16));                                   \
        cm = fmaxf(cm, __shfl_xor(cm, 32));                                   \
        if (l < 16) cls[(T)][l][w] = cm;                                      \
    }

__global__ __launch_bounds__(256, 2)
void chamfer_fused(const h8* __restrict__ Xpk, const h8* __restrict__ Ypk,
                   const float* __restrict__ phX, const float* __restrict__ phY,
                   float* __restrict__ mp, unsigned int* __restrict__ colkey)
{
    __shared__ float cls[64][16][4];     // [tile][col-lane][wave] = 16 KB

    const int phys = blockIdx.x;
    const int lg   = (phys & 7) * 64 + (phys >> 3);
    const int xb   = lg & 7;             // 8 row-blocks of 256 rows
    const int rest = lg >> 3;
    const int mh   = rest & 1;           // M-half
    const int b    = rest >> 1;          // batch

    const int tid = threadIdx.x;
    const int w   = tid >> 6;
    const int l   = tid & 63;
    const int lc  = l & 15;
    const int g   = l >> 4;

    const int row0 = xb * 256 + w * 64;                   // within batch
    const size_t pt0 = ((size_t)b * NM + row0) >> 4;      // global 16-row tile
    const h8* pa = Xpk + pt0 * 64 + l;
    h8 a0 = pa[0], a1 = pa[64], a2 = pa[128], a3 = pa[192];

    // Constant C-seed tuples: hx_i[r] = -0.5*||x||^2[row0 + 16i + 4g + r]
    const float* hxb = phX + (size_t)b * NM + row0 + g * 4;
    f4 hx0 = *(const f4*)(hxb);
    f4 hx1 = *(const f4*)(hxb + 16);
    f4 hx2 = *(const f4*)(hxb + 32);
    f4 hx3 = *(const f4*)(hxb + 48);
#pragma unroll
    for (int r = 0; r < 4; ++r) {
        hx0[r] = -hx0[r]; hx1[r] = -hx1[r];
        hx2[r] = -hx2[r]; hx3[r] = -hx3[r];
    }

    const int mt0 = mh * 64;                              // 64 tiles per half
    const h8*    qb  = Ypk + ((size_t)b * (NM / 16) + mt0) * 64 + l;
    const float* php = phY + (size_t)b * NM + mt0 * 16 + lc;

    const float NEGINF = -3.0e38f;
    f4 mx0 = {NEGINF, NEGINF, NEGINF, NEGINF};
    f4 mx1 = mx0, mx2 = mx0, mx3 = mx0;

    // 4-deep register prefetch pipeline over 64 tiles
    h8 b0 = qb[0], b1 = qb[64], b2 = qb[128], b3 = qb[192];
    float c0 = php[0], c1 = php[16], c2 = php[32], c3 = php[48];

    int t = 0;
    for (; t < 60; t += 4) {
        qb += 4 * 64; php += 4 * 16;
        h8 n0 = qb[0], n1 = qb[64], n2 = qb[128], n3 = qb[192];
        float d0 = php[0], d1 = php[16], d2 = php[32], d3 = php[48];
        PASS1(b0, c0, t + 0);
        PASS1(b1, c1, t + 1);
        PASS1(b2, c2, t + 2);
        PASS1(b3, c3, t + 3);
        b0 = n0; b1 = n1; b2 = n2; b3 = n3;
        c0 = d0; c1 = d1; c2 = d2; c3 = d3;
    }
    PASS1(b0, c0, 60);       // tail batch
    PASS1(b1, c1, 61);
    PASS1(b2, c2, 62);
    PASS1(b3, c3, 63);

    // ---- row side: reduce max across the 16 column-lanes, store s-max ----
#pragma unroll
    for (int m = 1; m <= 8; m <<= 1) {
#pragma unroll
        for (int r = 0; r < 4; ++r) {
            mx0[r] = fmaxf(mx0[r], __shfl_xor(mx0[r], m));
            mx1[r] = fmaxf(mx1[r], __shfl_xor(mx1[r], m));
            mx2[r] = fmaxf(mx2[r], __shfl_xor(mx2[r], m));
            mx3[r] = fmaxf(mx3[r], __shfl_xor(mx3[r], m));
        }
    }
    if (lc == 0) {   // rows row0 + i*16 + g*4 .. +3
        float* out = mp + ((size_t)mh * B_SZ + b) * NM + row0 + (g << 2);
        *(f4*)(out)      = mx0;
        *(f4*)(out + 16) = mx1;
        *(f4*)(out + 32) = mx2;
        *(f4*)(out + 48) = mx3;
    }

    // ---- col side: cross-wave combine + one atomicMin per column ----
    __syncthreads();
    unsigned int* ck = colkey + (size_t)b * NM + mh * 1024;
#pragma unroll
    for (int k = 0; k < 4; ++k) {
        int c = tid + k * 256;           // 0..1023 within the half
        f4 v = *(const f4*)&cls[c >> 4][c & 15][0];
        float m = fmaxf(fmaxf(v[0], v[1]), fmaxf(v[2], v[3]));
        atomicMin(&ck[c], __float_as_uint(m));
    }
}

// ---------------------------------------------------------------------------
// Single merged finalize: d2 = max(0, -2*smax); sqrt; block tree-sum;
// deterministic fixed-point u64 atomicAdd (integer adds commute exactly);
// last-done block (atomic counter + threadfence ordering) writes out[0].
// 32768 work items = 128 blocks x 256 (branch is block-uniform).
// ---------------------------------------------------------------------------
__global__ __launch_bounds__(256)
void finalize_one(const float* __restrict__ mp,
                  const unsigned int* __restrict__ colkey,
                  unsigned long long* __restrict__ acc,
                  float* __restrict__ out)
{
    const int i = blockIdx.x * 256 + threadIdx.x;   // 0..32767
    float s = 0.f;
    if (i < 16384) {
        f4 p0 = ((const f4*)mp)[i];
        f4 p1 = ((const f4*)mp)[16384 + i];
#pragma unroll
        for (int r = 0; r < 4; ++r) {
            float sm = fmaxf(p0[r], p1[r]);
            s += sqrtf(fmaxf(-2.f * sm, 0.f));
        }
    } else {
        const uint4* ck = (const uint4*)colkey;
        uint4 k = ck[i - 16384];
        s += sqrtf(fmaxf(-2.f * __uint_as_float(k.x), 0.f));
        s += sqrtf(fmaxf(-2.f * __uint_as_float(k.y), 0.f));
        s += sqrtf(fmaxf(-2.f * __uint_as_float(k.z), 0.f));
        s += sqrtf(fmaxf(-2.f * __uint_as_float(k.w), 0.f));
    }
    __shared__ float wsum[4];
#pragma unroll
    for (int o = 32; o > 0; o >>= 1) s += __shfl_down(s, o, 64);
    if ((threadIdx.x & 63) == 0) wsum[threadIdx.x >> 6] = s;
    __syncthreads();
    if (threadIdx.x == 0) {
        float bs = wsum[0] + wsum[1] + wsum[2] + wsum[3];
        unsigned long long v =
            (unsigned long long)llrint((double)bs * 1048576.0);
        atomicAdd(&acc[0], v);
        __threadfence();
        unsigned long long c = atomicAdd(&acc[1], 1ULL);
        if (c == 127ULL) {               // last block: total is final
            unsigned long long tot = atomicAdd(&acc[0], 0ULL);
            out[0] = (float)((double)tot * (1.0 / (131072.0 * 1048576.0)));
        }
    }
}

extern "C" void kernel_launch(void* const* d_in, const int* in_sizes, int n_in,
                              void* d_out, int out_size, void* d_ws, size_t ws_size,
                              hipStream_t stream) {
    const float* X = (const float*)d_in[0];
    const float* Y = (const float*)d_in[1];

    // ws: mp 131072 f | colkey 65536 u32 | acc 2 u64 | ph 131072 f | packed
    float*              ws     = (float*)d_ws;
    float*              mp     = ws;                           // 131072 f
    unsigned int*       colkey = (unsigned int*)(mp + 131072); // 65536 u32
    unsigned long long* acc    = (unsigned long long*)(colkey + 65536); // 16 B
    float*              ph     = (float*)(acc + 2);            // 131072 f
    h8*                 Xpk    = (h8*)(ph + 131072);           // 4.19 MB
    h8*                 Ypk    = Xpk + 262144;                 // 4.19 MB

    dim3 pgrid(1024, 2);
    pack_kernel<<<pgrid, 256, 0, stream>>>(X, Y, Xpk, Ypk, ph, ph + 65536,
                                           colkey, acc);

    chamfer_fused<<<8 * B_SZ * 2, 256, 0, stream>>>(Xpk, Ypk, ph, ph + 65536,
                                                    mp, colkey);

    finalize_one<<<128, 256, 0, stream>>>(mp, colkey, acc, (float*)d_out);
}